// Round 9
// baseline (294.286 us; speedup 1.0000x reference)
//
#include <hip/hip_runtime.h>
#include <hip/hip_bf16.h>
#include <stdint.h>

#define B_ 64
#define T_ 20
#define N_ 8192
#define E_ 128
#define H_ 128
#define G4 512
#define SPLITK 8

typedef short bf16x8 __attribute__((ext_vector_type(8)));
typedef float f32x4 __attribute__((ext_vector_type(4)));

__device__ __forceinline__ float sigmoidf_(float x){ return 1.0f/(1.0f+expf(-x)); }

__device__ __forceinline__ unsigned short f2bf(float f){
  union { float f; uint32_t u; } v; v.f = f;
  uint32_t u = v.u;
  uint32_t r = (u + 0x7FFFu + ((u >> 16) & 1u)) >> 16;
  return (unsigned short)r;
}
__device__ __forceinline__ uint32_t pk2(float a, float b){
  return (uint32_t)f2bf(a) | ((uint32_t)f2bf(b) << 16);
}
__device__ __forceinline__ float bf2f(unsigned short s){
  union { uint32_t u; float f; } v; v.u = ((uint32_t)s) << 16; return v.f;
}

// ---------------- 1. transpose W1,W2 -> W12T bf16; zero split-K semaphores
__global__ void k_transpose(const float* __restrict__ W1, const float* __restrict__ W2,
                            unsigned short* __restrict__ W12T, unsigned* __restrict__ sems){
  if (blockIdx.x == 0 && threadIdx.x < 64) sems[threadIdx.x] = 0;
  __shared__ float t1[128][33];
  __shared__ float t2[128][33];
  int n0 = blockIdx.x * 32;
  int tid = threadIdx.x;           // 256
  int nl = tid & 31, eg = tid >> 5;
  for (int i = 0; i < 16; i++){
    int e = eg * 16 + i;
    t1[e][nl] = W1[(size_t)e*N_ + n0 + nl];
    t2[e][nl] = W2[(size_t)e*N_ + n0 + nl];
  }
  __syncthreads();
  for (int n = 0; n < 32; n++){
    float v = (tid < 128) ? t1[tid][n] : t2[tid-128][n];
    W12T[(size_t)(n0+n)*256 + tid] = f2bf(v);
  }
}

// ---------------- 2. sparse MLP: basket = max(relu(W1sum+b1), relu(W2sum+b2))
__global__ void k_mlp(const float* __restrict__ x, const int* __restrict__ seq_len,
                      const unsigned short* __restrict__ W12T, const float* __restrict__ b1,
                      const float* __restrict__ b2, float* __restrict__ basket){
  int bt = blockIdx.x;
  int b = bt / T_, t = bt % T_;
  int tid = threadIdx.x;           // 256
  if (t >= seq_len[b]){            // zero-fill so downstream reads defined data
    if (tid < 128) basket[(size_t)bt*E_ + tid] = 0.f;
    return;
  }
  __shared__ int idxs[1024];
  __shared__ int cnt;
  __shared__ float e2s[128];
  if (tid == 0) cnt = 0;
  __syncthreads();
  const float4* xr = (const float4*)(x + (size_t)bt * N_);
  for (int i = 0; i < 8; i++){
    float4 v = xr[i*256 + tid];
    int base = (i*256 + tid)*4;
    if (v.x != 0.f){ int q = atomicAdd(&cnt,1); idxs[q] = base;   }
    if (v.y != 0.f){ int q = atomicAdd(&cnt,1); idxs[q] = base+1; }
    if (v.z != 0.f){ int q = atomicAdd(&cnt,1); idxs[q] = base+2; }
    if (v.w != 0.f){ int q = atomicAdd(&cnt,1); idxs[q] = base+3; }
  }
  __syncthreads();
  int m = cnt; if (m > 1024) m = 1024;
  float acc = (tid < 128) ? b1[tid] : b2[tid-128];
  int i = 0;
  for (; i + 8 <= m; i += 8){
    int j0 = idxs[i+0], j1 = idxs[i+1], j2 = idxs[i+2], j3 = idxs[i+3];
    int j4 = idxs[i+4], j5 = idxs[i+5], j6 = idxs[i+6], j7 = idxs[i+7];
    float v0 = bf2f(W12T[(size_t)j0*256 + tid]);
    float v1 = bf2f(W12T[(size_t)j1*256 + tid]);
    float v2 = bf2f(W12T[(size_t)j2*256 + tid]);
    float v3 = bf2f(W12T[(size_t)j3*256 + tid]);
    float v4 = bf2f(W12T[(size_t)j4*256 + tid]);
    float v5 = bf2f(W12T[(size_t)j5*256 + tid]);
    float v6 = bf2f(W12T[(size_t)j6*256 + tid]);
    float v7 = bf2f(W12T[(size_t)j7*256 + tid]);
    acc += ((v0+v1)+(v2+v3)) + ((v4+v5)+(v6+v7));
  }
  for (; i < m; i++)
    acc += bf2f(W12T[(size_t)idxs[i]*256 + tid]);
  acc = fmaxf(acc, 0.f);
  if (tid >= 128) e2s[tid-128] = acc;
  __syncthreads();
  if (tid < 128) basket[(size_t)bt*E_ + tid] = fmaxf(acc, e2s[tid]);
}

// ---------------- 3. fused x-projection + LSTM (one block per batch row)
__global__ void __launch_bounds__(512, 1)
k_lstmx(const int* __restrict__ seq_len, const float* __restrict__ basket,
        const float* __restrict__ W_ih, const float* __restrict__ b_ih,
        const float* __restrict__ b_hh, const float* __restrict__ W_hh,
        float* __restrict__ hn){
  int b = blockIdx.x;
  int L = seq_len[b];
  int j = threadIdx.x;              // 512
  __shared__ float bsk[T_][E_];     // 10 KB  (basket rows; zero for invalid t)
  __shared__ float XpL[T_][G4];     // 40 KB  (x-projection, LDS-resident)
  __shared__ float hs[128];
  __shared__ float gs[512];
  for (int idx = j; idx < T_*E_; idx += 512)
    bsk[idx>>7][idx&127] = basket[((size_t)b*T_ + (idx>>7))*E_ + (idx&127)];
  __syncthreads();
  // x-projection: thread j computes gate j for all 20 t (static indices; invalid t harmless)
  {
    float bias = b_ih[j] + b_hh[j];
    float accv[T_];
    #pragma unroll
    for (int tt = 0; tt < T_; tt++) accv[tt] = bias;
    const float4* wr = (const float4*)(W_ih + (size_t)j * E_);
    for (int k4 = 0; k4 < 32; k4++){
      float4 w = wr[k4];
      #pragma unroll
      for (int tt = 0; tt < T_; tt++){
        float4 h = *(const float4*)&bsk[tt][k4*4];
        accv[tt] += w.x*h.x + w.y*h.y + w.z*h.z + w.w*h.w;
      }
    }
    #pragma unroll
    for (int tt = 0; tt < T_; tt++) XpL[tt][j] = accv[tt];
  }
  // LSTM
  float4 whh[32];
  const float4* wr2 = (const float4*)(W_hh + (size_t)j * H_);
  #pragma unroll
  for (int k = 0; k < 32; k++) whh[k] = wr2[k];
  if (j < 128) hs[j] = 0.f;
  float c = 0.f;
  __syncthreads();                  // covers XpL writes + hs init
  for (int t = 0; t < L; t++){
    float s0 = XpL[t][j], s1 = 0.f, s2 = 0.f, s3 = 0.f;
    #pragma unroll
    for (int k = 0; k < 32; k += 4){
      float4 w, h;
      w = whh[k+0]; h = *(const float4*)&hs[k*4+ 0]; s0 += w.x*h.x + w.y*h.y + w.z*h.z + w.w*h.w;
      w = whh[k+1]; h = *(const float4*)&hs[k*4+ 4]; s1 += w.x*h.x + w.y*h.y + w.z*h.z + w.w*h.w;
      w = whh[k+2]; h = *(const float4*)&hs[k*4+ 8]; s2 += w.x*h.x + w.y*h.y + w.z*h.z + w.w*h.w;
      w = whh[k+3]; h = *(const float4*)&hs[k*4+12]; s3 += w.x*h.x + w.y*h.y + w.z*h.z + w.w*h.w;
    }
    gs[j] = (s0 + s1) + (s2 + s3);
    __syncthreads();
    if (j < 128){
      float i_ = gs[j], f_ = gs[128+j], gg = gs[256+j], o_ = gs[384+j];
      c = sigmoidf_(f_)*c + sigmoidf_(i_)*tanhf(gg);
      hs[j] = sigmoidf_(o_)*tanhf(c);
    }
    __syncthreads();
  }
  if (j < 128) hn[(size_t)b*H_ + j] = hs[j];
}

// ---------------- 4. p = sigmoid(hn @ W_out^T) via MFMA -> bf16
__global__ void k_pout(const float* __restrict__ hn, const float* __restrict__ W_out,
                       unsigned short* __restrict__ pbf){
  __shared__ unsigned short hb[64*128];   // bf16, XOR-swizzled 16B blocks
  int tid = threadIdx.x;                  // 256
  {
    int row = tid >> 2;
    int k16 = (tid & 3) * 32;
    const float4* hr = (const float4*)(hn + (size_t)row*H_ + k16);
    #pragma unroll
    for (int i = 0; i < 4; i++){
      float4 a = hr[i*2], bq = hr[i*2+1];
      uint4 u; u.x = pk2(a.x,a.y); u.y = pk2(a.z,a.w); u.z = pk2(bq.x,bq.y); u.w = pk2(bq.z,bq.w);
      int blk = (k16 >> 3) + i;
      *(uint4*)&hb[row*128 + ((blk ^ (row & 7)) * 8)] = u;
    }
  }
  __syncthreads();
  int w = tid >> 6, l = tid & 63;
  int n0 = blockIdx.x * 128;
  f32x4 acc[8];
  #pragma unroll
  for (int i = 0; i < 8; i++) acc[i] = (f32x4){0.f,0.f,0.f,0.f};
  int row = w*16 + (l & 15);
  #pragma unroll
  for (int ks = 0; ks < 4; ks++){
    int kk = ks*32 + (l >> 4)*8;
    int blk = kk >> 3;
    bf16x8 af = *(bf16x8*)&hb[row*128 + ((blk ^ (row & 7)) * 8)];
    #pragma unroll
    for (int nt = 0; nt < 8; nt++){
      int n = n0 + nt*16 + (l & 15);
      const float4* wp = (const float4*)(W_out + (size_t)n*H_ + kk);
      float4 wa = wp[0], wb = wp[1];
      union { uint4 u; bf16x8 v; } cc;
      cc.u.x = pk2(wa.x,wa.y); cc.u.y = pk2(wa.z,wa.w);
      cc.u.z = pk2(wb.x,wb.y); cc.u.w = pk2(wb.z,wb.w);
      acc[nt] = __builtin_amdgcn_mfma_f32_16x16x32_bf16(af, cc.v, acc[nt], 0, 0, 0);
    }
  }
  #pragma unroll
  for (int nt = 0; nt < 8; nt++){
    int n = n0 + nt*16 + (l & 15);
    #pragma unroll
    for (int r = 0; r < 4; r++){
      int rr = w*16 + (l >> 4)*4 + r;
      float pv = 1.f/(1.f + expf(-acc[nt][r]));
      pbf[(size_t)rr*N_ + n] = f2bf(pv);
    }
  }
}

// ---------------- 5. Cp[s] = p @ A[slice]  + semaphore-fused final blend
__global__ void __launch_bounds__(512, 4)
k_gemmf(const unsigned short* __restrict__ pbf, const float* __restrict__ Ag,
        float* __restrict__ Cp, const float* __restrict__ I_B,
        float* __restrict__ out, unsigned* __restrict__ sems){
  __shared__ unsigned short Abf0[128*64];
  __shared__ unsigned short Abf1[128*64];
  __shared__ unsigned short pt0[64*64];
  __shared__ unsigned short pt1[64*64];
  __shared__ unsigned lastf;
  int tid = threadIdx.x;                   // 512
  int nb = blockIdx.x & 63, ks = blockIdx.x >> 6;
  int n0 = nb * 128;
  int kbase = ks * (N_ / SPLITK);
  int sn = tid & 127, kq = tid >> 7;
  int prow = tid >> 3, c8 = tid & 7;
  int w = tid >> 6, l = tid & 63;
  int wm = w >> 2, wn = w & 3;
  f32x4 acc[2][2];
  #pragma unroll
  for (int i = 0; i < 2; i++)
    #pragma unroll
    for (int q = 0; q < 2; q++) acc[i][q] = (f32x4){0.f,0.f,0.f,0.f};
  float* Cout = Cp + (size_t)ks * (B_ * N_);
  const int NSTEP = (N_ / SPLITK) / 64;    // 16

  float aA[16], aB[16];
  uint4 pA, pB;

  auto issue = [&](float* ar, uint4& pr, int kb){
    pr = *(const uint4*)&pbf[(size_t)prow*N_ + kb + c8*8];
    #pragma unroll
    for (int i = 0; i < 4; i++){
      const float* base = Ag + (size_t)(kb + kq*16 + i*4)*N_ + n0 + sn;
      ar[i*4+0] = base[0];
      ar[i*4+1] = base[(size_t)N_];
      ar[i*4+2] = base[(size_t)2*N_];
      ar[i*4+3] = base[(size_t)3*N_];
    }
  };
  auto stage = [&](unsigned short* abf, unsigned short* ptb, const float* ar, const uint4& pr){
    *(uint4*)&ptb[prow*64 + ((c8*8) ^ ((prow & 7)*8))] = pr;
    #pragma unroll
    for (int i = 0; i < 4; i++){
      int k = kq*16 + i*4;
      uint2 u; u.x = pk2(ar[i*4+0], ar[i*4+1]); u.y = pk2(ar[i*4+2], ar[i*4+3]);
      *(uint2*)&abf[sn*64 + (k ^ ((sn & 7)*8))] = u;
    }
  };
  auto compute = [&](const unsigned short* abf, const unsigned short* ptb){
    #pragma unroll
    for (int kc = 0; kc < 64; kc += 32){
      int ko = kc + (l >> 4)*8;
      bf16x8 af[2], bfr[2];
      #pragma unroll
      for (int mi = 0; mi < 2; mi++){
        int r = wm*32 + mi*16 + (l & 15);
        af[mi] = *(const bf16x8*)&ptb[r*64 + (ko ^ ((r & 7)*8))];
      }
      #pragma unroll
      for (int ni = 0; ni < 2; ni++){
        int n = wn*32 + ni*16 + (l & 15);
        bfr[ni] = *(const bf16x8*)&abf[n*64 + (ko ^ ((n & 7)*8))];
      }
      #pragma unroll
      for (int mi = 0; mi < 2; mi++)
        #pragma unroll
        for (int ni = 0; ni < 2; ni++)
          acc[mi][ni] = __builtin_amdgcn_mfma_f32_16x16x32_bf16(af[mi], bfr[ni], acc[mi][ni], 0, 0, 0);
    }
  };

  issue(aA, pA, kbase);
  for (int s = 0; s < NSTEP; s += 2){
    if (s + 1 < NSTEP) issue(aB, pB, kbase + (s+1)*64);
    stage(Abf0, pt0, aA, pA);
    asm volatile("s_waitcnt lgkmcnt(0)" ::: "memory");
    __builtin_amdgcn_sched_barrier(0);
    __builtin_amdgcn_s_barrier();
    __builtin_amdgcn_sched_barrier(0);
    compute(Abf0, pt0);
    if (s + 2 < NSTEP) issue(aA, pA, kbase + (s+2)*64);
    stage(Abf1, pt1, aB, pB);
    asm volatile("s_waitcnt lgkmcnt(0)" ::: "memory");
    __builtin_amdgcn_sched_barrier(0);
    __builtin_amdgcn_s_barrier();
    __builtin_amdgcn_sched_barrier(0);
    compute(Abf1, pt1);
  }

  #pragma unroll
  for (int mi = 0; mi < 2; mi++)
    #pragma unroll
    for (int ni = 0; ni < 2; ni++){
      int n = n0 + wn*32 + ni*16 + (l & 15);
      #pragma unroll
      for (int r = 0; r < 4; r++){
        int rr = wm*32 + mi*16 + (l >> 4)*4 + r;
        Cout[(size_t)rr*N_ + n] = acc[mi][ni][r];
      }
    }

  // ---- split-K semaphore: 8th arriver for this nb does the final blend ----
  __threadfence();                         // release this block's slab stores
  __syncthreads();                         // all threads' stores+fences done
  if (tid == 0){
    unsigned old = atomicAdd(&sems[nb], 1);
    lastf = (old == SPLITK-1) ? 1u : 0u;
  }
  __syncthreads();
  if (lastf){
    __threadfence();                       // acquire: see other blocks' slabs
    #pragma unroll
    for (int g = 0; g < 4; g++){
      int e = g*512 + tid;                 // 2048 items = 64 rows x 32 float4
      int row = e >> 5, c4 = e & 31;
      size_t off = (size_t)row*N_ + n0 + c4*4;
      float4 cv = {0.f,0.f,0.f,0.f};
      #pragma unroll
      for (int s2 = 0; s2 < SPLITK; s2++){
        float4 v = *(const float4*)&Cp[(size_t)s2*(B_*N_) + off];
        cv.x += v.x; cv.y += v.y; cv.z += v.z; cv.w += v.w;
      }
      ushort4 pu = *(const ushort4*)&pbf[off];
      float4 ib = *(const float4*)&I_B[n0 + c4*4];
      float p0 = bf2f(pu.x), p1 = bf2f(pu.y), p2 = bf2f(pu.z), p3 = bf2f(pu.w);
      float4 o;
      o.x = 0.5f*p0 + 0.5f*(p0*fmaxf(ib.x,0.f) + fmaxf(cv.x,0.f));
      o.y = 0.5f*p1 + 0.5f*(p1*fmaxf(ib.y,0.f) + fmaxf(cv.y,0.f));
      o.z = 0.5f*p2 + 0.5f*(p2*fmaxf(ib.z,0.f) + fmaxf(cv.z,0.f));
      o.w = 0.5f*p3 + 0.5f*(p3*fmaxf(ib.w,0.f) + fmaxf(cv.w,0.f));
      *(float4*)&out[off] = o;
    }
  }
}

extern "C" void kernel_launch(void* const* d_in, const int* in_sizes, int n_in,
                              void* d_out, int out_size, void* d_ws, size_t ws_size,
                              hipStream_t stream) {
  const float* x     = (const float*)d_in[0];
  const int*   seq   = (const int*)  d_in[1];
  const float* A     = (const float*)d_in[2];
  const float* W1    = (const float*)d_in[3];
  const float* b1    = (const float*)d_in[4];
  const float* W2    = (const float*)d_in[5];
  const float* b2    = (const float*)d_in[6];
  const float* W_ih  = (const float*)d_in[7];
  const float* W_hh  = (const float*)d_in[8];
  const float* b_ih  = (const float*)d_in[9];
  const float* b_hh  = (const float*)d_in[10];
  const float* W_out = (const float*)d_in[11];
  const float* I_B   = (const float*)d_in[12];
  float* out = (float*)d_out;

  float* ws = (float*)d_ws;
  unsigned short* W12T = (unsigned short*)ws;            // 8192*256 bf16 = 1,048,576 f
  float* basket = ws + 1048576;                          // 1280*128 = 163,840 f
  float* hn     = basket + 163840;                       // 64*128   =   8,192 f
  float* Cp     = hn + 8192;                             // 8*64*8192 = 4,194,304 f
  unsigned short* pbf = (unsigned short*)(Cp + 4194304); // 64*8192 bf16 = 262,144 f
  unsigned* sems = (unsigned*)(Cp + 4194304 + 262144);   // 64 u32

  k_transpose<<<256, 256, 0, stream>>>(W1, W2, W12T, sems);
  k_mlp      <<<1280,256, 0, stream>>>(x, seq, W12T, b1, b2, basket);
  k_lstmx    <<<64,  512, 0, stream>>>(seq, basket, W_ih, b_ih, b_hh, W_hh, hn);
  k_pout     <<<64,  256, 0, stream>>>(hn, W_out, pbf);
  k_gemmf    <<<64*SPLITK, 512, 0, stream>>>(pbf, A, Cp, I_B, out, sems);
}

// Round 10
// 149.811 us; speedup vs baseline: 1.9644x; 1.9644x over previous
//
#include <hip/hip_runtime.h>
#include <hip/hip_bf16.h>
#include <stdint.h>

#define B_ 64
#define T_ 20
#define N_ 8192
#define E_ 128
#define H_ 128
#define G4 512
#define SPLITK 8

typedef short bf16x8 __attribute__((ext_vector_type(8)));
typedef float f32x4 __attribute__((ext_vector_type(4)));

__device__ __forceinline__ float sigmoidf_(float x){ return 1.0f/(1.0f+expf(-x)); }

__device__ __forceinline__ unsigned short f2bf(float f){
  union { float f; uint32_t u; } v; v.f = f;
  uint32_t u = v.u;
  uint32_t r = (u + 0x7FFFu + ((u >> 16) & 1u)) >> 16;
  return (unsigned short)r;
}
__device__ __forceinline__ uint32_t pk2(float a, float b){
  return (uint32_t)f2bf(a) | ((uint32_t)f2bf(b) << 16);
}
__device__ __forceinline__ float bf2f(unsigned short s){
  union { uint32_t u; float f; } v; v.u = ((uint32_t)s) << 16; return v.f;
}

// ---------------- 1. transpose W1,W2 -> W12T bf16
__global__ void k_transpose(const float* __restrict__ W1, const float* __restrict__ W2,
                            unsigned short* __restrict__ W12T){
  __shared__ float t1[128][33];
  __shared__ float t2[128][33];
  int n0 = blockIdx.x * 32;
  int tid = threadIdx.x;           // 256
  int nl = tid & 31, eg = tid >> 5;
  for (int i = 0; i < 16; i++){
    int e = eg * 16 + i;
    t1[e][nl] = W1[(size_t)e*N_ + n0 + nl];
    t2[e][nl] = W2[(size_t)e*N_ + n0 + nl];
  }
  __syncthreads();
  for (int n = 0; n < 32; n++){
    float v = (tid < 128) ? t1[tid][n] : t2[tid-128][n];
    W12T[(size_t)(n0+n)*256 + tid] = f2bf(v);
  }
}

// ---------------- 2. sparse MLP
__global__ void k_mlp(const float* __restrict__ x, const int* __restrict__ seq_len,
                      const unsigned short* __restrict__ W12T, const float* __restrict__ b1,
                      const float* __restrict__ b2, float* __restrict__ basket){
  int bt = blockIdx.x;
  int b = bt / T_, t = bt % T_;
  int tid = threadIdx.x;           // 256
  if (t >= seq_len[b]){
    if (tid < 128) basket[(size_t)bt*E_ + tid] = 0.f;
    return;
  }
  __shared__ int idxs[1024];
  __shared__ int cnt;
  __shared__ float e2s[128];
  if (tid == 0) cnt = 0;
  __syncthreads();
  const float4* xr = (const float4*)(x + (size_t)bt * N_);
  for (int i = 0; i < 8; i++){
    float4 v = xr[i*256 + tid];
    int base = (i*256 + tid)*4;
    if (v.x != 0.f){ int q = atomicAdd(&cnt,1); idxs[q] = base;   }
    if (v.y != 0.f){ int q = atomicAdd(&cnt,1); idxs[q] = base+1; }
    if (v.z != 0.f){ int q = atomicAdd(&cnt,1); idxs[q] = base+2; }
    if (v.w != 0.f){ int q = atomicAdd(&cnt,1); idxs[q] = base+3; }
  }
  __syncthreads();
  int m = cnt; if (m > 1024) m = 1024;
  float acc = (tid < 128) ? b1[tid] : b2[tid-128];
  int i = 0;
  for (; i + 8 <= m; i += 8){
    int j0 = idxs[i+0], j1 = idxs[i+1], j2 = idxs[i+2], j3 = idxs[i+3];
    int j4 = idxs[i+4], j5 = idxs[i+5], j6 = idxs[i+6], j7 = idxs[i+7];
    float v0 = bf2f(W12T[(size_t)j0*256 + tid]);
    float v1 = bf2f(W12T[(size_t)j1*256 + tid]);
    float v2 = bf2f(W12T[(size_t)j2*256 + tid]);
    float v3 = bf2f(W12T[(size_t)j3*256 + tid]);
    float v4 = bf2f(W12T[(size_t)j4*256 + tid]);
    float v5 = bf2f(W12T[(size_t)j5*256 + tid]);
    float v6 = bf2f(W12T[(size_t)j6*256 + tid]);
    float v7 = bf2f(W12T[(size_t)j7*256 + tid]);
    acc += ((v0+v1)+(v2+v3)) + ((v4+v5)+(v6+v7));
  }
  for (; i < m; i++)
    acc += bf2f(W12T[(size_t)idxs[i]*256 + tid]);
  acc = fmaxf(acc, 0.f);
  if (tid >= 128) e2s[tid-128] = acc;
  __syncthreads();
  if (tid < 128) basket[(size_t)bt*E_ + tid] = fmaxf(acc, e2s[tid]);
}

// ---------------- 3. fused x-projection + LSTM (one block per batch row)
__global__ void __launch_bounds__(512, 1)
k_lstmx(const int* __restrict__ seq_len, const float* __restrict__ basket,
        const float* __restrict__ W_ih, const float* __restrict__ b_ih,
        const float* __restrict__ b_hh, const float* __restrict__ W_hh,
        float* __restrict__ hn){
  int b = blockIdx.x;
  int L = seq_len[b];
  int j = threadIdx.x;              // 512
  __shared__ float bsk[T_][E_];
  __shared__ float XpL[T_][G4];
  __shared__ float hs[128];
  __shared__ float gs[512];
  for (int idx = j; idx < T_*E_; idx += 512)
    bsk[idx>>7][idx&127] = basket[((size_t)b*T_ + (idx>>7))*E_ + (idx&127)];
  __syncthreads();
  {
    float bias = b_ih[j] + b_hh[j];
    float accv[T_];
    #pragma unroll
    for (int tt = 0; tt < T_; tt++) accv[tt] = bias;
    const float4* wr = (const float4*)(W_ih + (size_t)j * E_);
    for (int k4 = 0; k4 < 32; k4++){
      float4 w = wr[k4];
      #pragma unroll
      for (int tt = 0; tt < T_; tt++){
        float4 h = *(const float4*)&bsk[tt][k4*4];
        accv[tt] += w.x*h.x + w.y*h.y + w.z*h.z + w.w*h.w;
      }
    }
    #pragma unroll
    for (int tt = 0; tt < T_; tt++) XpL[tt][j] = accv[tt];
  }
  float4 whh[32];
  const float4* wr2 = (const float4*)(W_hh + (size_t)j * H_);
  #pragma unroll
  for (int k = 0; k < 32; k++) whh[k] = wr2[k];
  if (j < 128) hs[j] = 0.f;
  float c = 0.f;
  __syncthreads();
  for (int t = 0; t < L; t++){
    float s0 = XpL[t][j], s1 = 0.f, s2 = 0.f, s3 = 0.f;
    #pragma unroll
    for (int k = 0; k < 32; k += 4){
      float4 w, h;
      w = whh[k+0]; h = *(const float4*)&hs[k*4+ 0]; s0 += w.x*h.x + w.y*h.y + w.z*h.z + w.w*h.w;
      w = whh[k+1]; h = *(const float4*)&hs[k*4+ 4]; s1 += w.x*h.x + w.y*h.y + w.z*h.z + w.w*h.w;
      w = whh[k+2]; h = *(const float4*)&hs[k*4+ 8]; s2 += w.x*h.x + w.y*h.y + w.z*h.z + w.w*h.w;
      w = whh[k+3]; h = *(const float4*)&hs[k*4+12]; s3 += w.x*h.x + w.y*h.y + w.z*h.z + w.w*h.w;
    }
    gs[j] = (s0 + s1) + (s2 + s3);
    __syncthreads();
    if (j < 128){
      float i_ = gs[j], f_ = gs[128+j], gg = gs[256+j], o_ = gs[384+j];
      c = sigmoidf_(f_)*c + sigmoidf_(i_)*tanhf(gg);
      hs[j] = sigmoidf_(o_)*tanhf(c);
    }
    __syncthreads();
  }
  if (j < 128) hn[(size_t)b*H_ + j] = hs[j];
}

// ---------------- 4. p = sigmoid(hn @ W_out^T) via MFMA -> bf16
__global__ void k_pout(const float* __restrict__ hn, const float* __restrict__ W_out,
                       unsigned short* __restrict__ pbf){
  __shared__ unsigned short hb[64*128];
  int tid = threadIdx.x;                  // 256
  {
    int row = tid >> 2;
    int k16 = (tid & 3) * 32;
    const float4* hr = (const float4*)(hn + (size_t)row*H_ + k16);
    #pragma unroll
    for (int i = 0; i < 4; i++){
      float4 a = hr[i*2], bq = hr[i*2+1];
      uint4 u; u.x = pk2(a.x,a.y); u.y = pk2(a.z,a.w); u.z = pk2(bq.x,bq.y); u.w = pk2(bq.z,bq.w);
      int blk = (k16 >> 3) + i;
      *(uint4*)&hb[row*128 + ((blk ^ (row & 7)) * 8)] = u;
    }
  }
  __syncthreads();
  int w = tid >> 6, l = tid & 63;
  int n0 = blockIdx.x * 128;
  f32x4 acc[8];
  #pragma unroll
  for (int i = 0; i < 8; i++) acc[i] = (f32x4){0.f,0.f,0.f,0.f};
  int row = w*16 + (l & 15);
  #pragma unroll
  for (int ks = 0; ks < 4; ks++){
    int kk = ks*32 + (l >> 4)*8;
    int blk = kk >> 3;
    bf16x8 af = *(bf16x8*)&hb[row*128 + ((blk ^ (row & 7)) * 8)];
    #pragma unroll
    for (int nt = 0; nt < 8; nt++){
      int n = n0 + nt*16 + (l & 15);
      const float4* wp = (const float4*)(W_out + (size_t)n*H_ + kk);
      float4 wa = wp[0], wb = wp[1];
      union { uint4 u; bf16x8 v; } cc;
      cc.u.x = pk2(wa.x,wa.y); cc.u.y = pk2(wa.z,wa.w);
      cc.u.z = pk2(wb.x,wb.y); cc.u.w = pk2(wb.z,wb.w);
      acc[nt] = __builtin_amdgcn_mfma_f32_16x16x32_bf16(af, cc.v, acc[nt], 0, 0, 0);
    }
  }
  #pragma unroll
  for (int nt = 0; nt < 8; nt++){
    int n = n0 + nt*16 + (l & 15);
    #pragma unroll
    for (int r = 0; r < 4; r++){
      int rr = w*16 + (l >> 4)*4 + r;
      float pv = 1.f/(1.f + expf(-acc[nt][r]));
      pbf[(size_t)rr*N_ + n] = f2bf(pv);
    }
  }
}

// ---------------- 5. Cp[s] = p @ A[slice]  (explicit named registers, no arrays)
// ISSUE: 16 A-scalars into four f32x4 (static components only) + one uint4 p-row
#define ISSUE(a0,a1,a2,a3,pr,kb) do {                                          \
    pr = *(const uint4*)&pbf[(size_t)prow*N_ + (kb) + c8*8];                   \
    const float* bse = Ag + (size_t)(kb)*N_ + (size_t)kq*16*N_ + n0 + sn;      \
    a0.x = bse[0];              a0.y = bse[(size_t)N_];                        \
    a0.z = bse[(size_t)2*N_];   a0.w = bse[(size_t)3*N_];                      \
    a1.x = bse[(size_t)4*N_];   a1.y = bse[(size_t)5*N_];                      \
    a1.z = bse[(size_t)6*N_];   a1.w = bse[(size_t)7*N_];                      \
    a2.x = bse[(size_t)8*N_];   a2.y = bse[(size_t)9*N_];                      \
    a2.z = bse[(size_t)10*N_];  a2.w = bse[(size_t)11*N_];                     \
    a3.x = bse[(size_t)12*N_];  a3.y = bse[(size_t)13*N_];                     \
    a3.z = bse[(size_t)14*N_];  a3.w = bse[(size_t)15*N_];                     \
  } while(0)

#define STAGE(abf,ptb,a0,a1,a2,a3,pr) do {                                     \
    *(uint4*)&ptb[prow*64 + ((c8*8) ^ ((prow & 7)*8))] = pr;                   \
    uint2 u0, u1, u2, u3;                                                      \
    u0.x = pk2(a0.x,a0.y); u0.y = pk2(a0.z,a0.w);                              \
    u1.x = pk2(a1.x,a1.y); u1.y = pk2(a1.z,a1.w);                              \
    u2.x = pk2(a2.x,a2.y); u2.y = pk2(a2.z,a2.w);                              \
    u3.x = pk2(a3.x,a3.y); u3.y = pk2(a3.z,a3.w);                              \
    int kb0 = kq*16;                                                           \
    *(uint2*)&abf[sn*64 + ((kb0+ 0) ^ ((sn & 7)*8))] = u0;                     \
    *(uint2*)&abf[sn*64 + ((kb0+ 4) ^ ((sn & 7)*8))] = u1;                     \
    *(uint2*)&abf[sn*64 + ((kb0+ 8) ^ ((sn & 7)*8))] = u2;                     \
    *(uint2*)&abf[sn*64 + ((kb0+12) ^ ((sn & 7)*8))] = u3;                     \
  } while(0)

#define SYNC_AND() do {                                                        \
    asm volatile("s_waitcnt lgkmcnt(0)" ::: "memory");                         \
    __builtin_amdgcn_sched_barrier(0);                                         \
    __builtin_amdgcn_s_barrier();                                              \
    __builtin_amdgcn_sched_barrier(0);                                         \
  } while(0)

__global__ void __launch_bounds__(512, 4)
k_gemm(const unsigned short* __restrict__ pbf, const float* __restrict__ Ag,
       float* __restrict__ Cp){
  __shared__ unsigned short Abf0[128*64];
  __shared__ unsigned short Abf1[128*64];
  __shared__ unsigned short pt0[64*64];
  __shared__ unsigned short pt1[64*64];
  int tid = threadIdx.x;                   // 512
  int nb = blockIdx.x & 63, ks = blockIdx.x >> 6;
  int n0 = nb * 128;
  int kbase = ks * (N_ / SPLITK);
  int sn = tid & 127, kq = tid >> 7;
  int prow = tid >> 3, c8 = tid & 7;
  int w = tid >> 6, l = tid & 63;
  int wm = w >> 2, wn = w & 3;
  f32x4 acc00 = {0,0,0,0}, acc01 = {0,0,0,0}, acc10 = {0,0,0,0}, acc11 = {0,0,0,0};
  float* Cout = Cp + (size_t)ks * (B_ * N_);
  const int NSTEP = (N_ / SPLITK) / 64;    // 16

  f32x4 aA0, aA1, aA2, aA3, aB0, aB1, aB2, aB3;
  uint4 pA, pB;

  auto compute = [&](const unsigned short* abf, const unsigned short* ptb){
    #pragma unroll
    for (int kc = 0; kc < 64; kc += 32){
      int ko = kc + (l >> 4)*8;
      bf16x8 af0, af1, bf0, bf1;
      {
        int r0 = wm*32 + (l & 15);
        int r1 = r0 + 16;
        af0 = *(const bf16x8*)&ptb[r0*64 + (ko ^ ((r0 & 7)*8))];
        af1 = *(const bf16x8*)&ptb[r1*64 + (ko ^ ((r1 & 7)*8))];
        int n0_ = wn*32 + (l & 15);
        int n1_ = n0_ + 16;
        bf0 = *(const bf16x8*)&abf[n0_*64 + (ko ^ ((n0_ & 7)*8))];
        bf1 = *(const bf16x8*)&abf[n1_*64 + (ko ^ ((n1_ & 7)*8))];
      }
      acc00 = __builtin_amdgcn_mfma_f32_16x16x32_bf16(af0, bf0, acc00, 0, 0, 0);
      acc01 = __builtin_amdgcn_mfma_f32_16x16x32_bf16(af0, bf1, acc01, 0, 0, 0);
      acc10 = __builtin_amdgcn_mfma_f32_16x16x32_bf16(af1, bf0, acc10, 0, 0, 0);
      acc11 = __builtin_amdgcn_mfma_f32_16x16x32_bf16(af1, bf1, acc11, 0, 0, 0);
    }
  };

  ISSUE(aA0,aA1,aA2,aA3,pA, kbase);
  for (int s = 0; s < NSTEP; s += 2){
    if (s + 1 < NSTEP) ISSUE(aB0,aB1,aB2,aB3,pB, kbase + (s+1)*64);
    STAGE(Abf0, pt0, aA0,aA1,aA2,aA3, pA);
    SYNC_AND();
    compute(Abf0, pt0);
    if (s + 2 < NSTEP) ISSUE(aA0,aA1,aA2,aA3,pA, kbase + (s+2)*64);
    STAGE(Abf1, pt1, aB0,aB1,aB2,aB3, pB);
    SYNC_AND();
    compute(Abf1, pt1);
  }

  {
    int n_a = n0 + wn*32 + (l & 15);
    int n_b = n_a + 16;
    int rbase = wm*32 + (l >> 4)*4;
    #pragma unroll
    for (int r = 0; r < 4; r++){
      Cout[(size_t)(rbase + r)*N_ + n_a]      = acc00[r];
      Cout[(size_t)(rbase + r)*N_ + n_b]      = acc01[r];
      Cout[(size_t)(rbase + 16 + r)*N_ + n_a] = acc10[r];
      Cout[(size_t)(rbase + 16 + r)*N_ + n_b] = acc11[r];
    }
  }
}

// ---------------- 6. final blend
__global__ void k_final(const unsigned short* __restrict__ pbf, const float* __restrict__ Cp,
                        const float* __restrict__ I_B, float* __restrict__ out){
  int idx = blockIdx.x*256 + threadIdx.x;
  ushort4 pu = ((const ushort4*)pbf)[idx];
  float4 cv = {0.f, 0.f, 0.f, 0.f};
  #pragma unroll
  for (int s = 0; s < SPLITK; s++){
    float4 v = ((const float4*)(Cp + (size_t)s * (B_ * N_)))[idx];
    cv.x += v.x; cv.y += v.y; cv.z += v.z; cv.w += v.w;
  }
  int n = (idx*4) & (N_-1);
  float4 ib = *(const float4*)&I_B[n];
  float4 o;
  float p0 = bf2f(pu.x), p1 = bf2f(pu.y), p2 = bf2f(pu.z), p3 = bf2f(pu.w);
  o.x = 0.5f*p0 + 0.5f*(p0*fmaxf(ib.x,0.f) + fmaxf(cv.x,0.f));
  o.y = 0.5f*p1 + 0.5f*(p1*fmaxf(ib.y,0.f) + fmaxf(cv.y,0.f));
  o.z = 0.5f*p2 + 0.5f*(p2*fmaxf(ib.z,0.f) + fmaxf(cv.z,0.f));
  o.w = 0.5f*p3 + 0.5f*(p3*fmaxf(ib.w,0.f) + fmaxf(cv.w,0.f));
  ((float4*)out)[idx] = o;
}

extern "C" void kernel_launch(void* const* d_in, const int* in_sizes, int n_in,
                              void* d_out, int out_size, void* d_ws, size_t ws_size,
                              hipStream_t stream) {
  const float* x     = (const float*)d_in[0];
  const int*   seq   = (const int*)  d_in[1];
  const float* A     = (const float*)d_in[2];
  const float* W1    = (const float*)d_in[3];
  const float* b1    = (const float*)d_in[4];
  const float* W2    = (const float*)d_in[5];
  const float* b2    = (const float*)d_in[6];
  const float* W_ih  = (const float*)d_in[7];
  const float* W_hh  = (const float*)d_in[8];
  const float* b_ih  = (const float*)d_in[9];
  const float* b_hh  = (const float*)d_in[10];
  const float* W_out = (const float*)d_in[11];
  const float* I_B   = (const float*)d_in[12];
  float* out = (float*)d_out;

  float* ws = (float*)d_ws;
  unsigned short* W12T = (unsigned short*)ws;            // 8192*256 bf16 = 1,048,576 f
  float* basket = ws + 1048576;                          // 1280*128 = 163,840 f
  float* hn     = basket + 163840;                       // 64*128   =   8,192 f
  float* Cp     = hn + 8192;                             // 8*64*8192 = 4,194,304 f
  unsigned short* pbf = (unsigned short*)(Cp + 4194304); // 64*8192 bf16

  k_transpose<<<256, 256, 0, stream>>>(W1, W2, W12T);
  k_mlp      <<<1280,256, 0, stream>>>(x, seq, W12T, b1, b2, basket);
  k_lstmx    <<<64,  512, 0, stream>>>(seq, basket, W_ih, b_ih, b_hh, W_hh, hn);
  k_pout     <<<64,  256, 0, stream>>>(hn, W_out, pbf);
  k_gemm     <<<64*SPLITK, 512, 0, stream>>>(pbf, A, Cp);
  k_final    <<<512, 256, 0, stream>>>(pbf, Cp, I_B, out);
}